// Round 9
// baseline (62.654 us; speedup 1.0000x reference)
//
#include <hip/hip_runtime.h>

#define BATCH 8
#define NATOM 256
#define DF    42
#define H1    64
#define H2    32

typedef float f32x4 __attribute__((ext_vector_type(4)));

__device__ __forceinline__ float softplus_f(float z) {
  return fmaxf(z, 0.f) + log1pf(expf(-fabsf(z)));
}

// ---------------- Kernel 1: per-atom mirrored MLP (fwd + analytic bwd) ----
// grid = B*N/4 blocks, 256 threads (4 waves). One wave per atom.
__global__ __launch_bounds__(256) void k1_mlp(
    const float* __restrict__ image,
    const float* __restrict__ W1, const float* __restrict__ b1,
    const float* __restrict__ W2, const float* __restrict__ b2,
    const float* __restrict__ W3, const float* __restrict__ b3,
    float* __restrict__ dG, float* __restrict__ Ei_ws) {
  __shared__ float sW1 [DF*H1];   // [d][h]
  __shared__ float sW1T[H1*DF];   // [h][d]
  __shared__ float sW2 [H1*H2];   // [h1][h2]
  __shared__ float sW2T[H2*H1];   // [h2][h1]
  __shared__ float sW3[H2], sb1[H1], sb2[H2];

  const int tid = threadIdx.x;
  for (int idx = tid; idx < DF*H1; idx += 256) {
    float w = W1[idx];
    sW1[idx] = w;
    sW1T[(idx & (H1-1))*DF + (idx >> 6)] = w;   // idx = d*64+h
  }
  for (int idx = tid; idx < H1*H2; idx += 256) {
    float w = W2[idx];
    sW2[idx] = w;
    sW2T[(idx & (H2-1))*H1 + (idx >> 5)] = w;   // idx = h1*32+h2
  }
  if (tid < H2)                    { sW3[tid] = W3[tid]; sb2[tid] = b2[tid]; }
  else if (tid >= 64 && tid < 128) { sb1[tid-64] = b1[tid-64]; }
  __syncthreads();

  const int lane = tid & 63;
  const int atom = blockIdx.x * 4 + (tid >> 6);      // 0..B*N-1

  float xv = (lane < DF) ? image[atom*DF + lane] : 0.f;

  // layer 1: z1[h] = b1[h] + sum_d x[d]*W1[d][h]   (lane = h)
  float z1 = sb1[lane];
  #pragma unroll
  for (int d = 0; d < DF; ++d)
    z1 = fmaf(__shfl(xv, d), sW1[d*H1 + lane], z1);
  float a1 = softplus_f(z1);

  // layer 2: lanes duplicated mod 32 (lane&31 = h2)
  const int h2l = lane & (H2-1);
  float z2 = sb2[h2l];
  #pragma unroll
  for (int h = 0; h < H1; ++h)
    z2 = fmaf(__shfl(a1, h), sW2[h*H2 + h2l], z2);
  float a2 = softplus_f(z2);

  // Ei = b3 + sum_h2 a2*W3 ;  g2 = sigmoid(z2)*W3 ; sigmoid(z)=1-exp(-softplus(z))
  float w3  = sW3[h2l];
  float eip = a2 * w3;
  #pragma unroll
  for (int off = 16; off; off >>= 1) eip += __shfl_xor(eip, off);
  float g2 = (1.f - expf(-a2)) * w3;

  // g1[h] = sigmoid(z1[h]) * sum_h2 g2[h2]*W2[h][h2]
  float t1 = 0.f;
  #pragma unroll
  for (int h2 = 0; h2 < H2; ++h2)
    t1 = fmaf(__shfl(g2, h2), sW2T[h2*H1 + lane], t1);
  float g1 = (1.f - expf(-a1)) * t1;

  // dG[d] = sum_h g1[h]*W1[d][h]    (lane = d, lanes 0..41)
  const int dl = (lane < DF) ? lane : 0;
  float s = 0.f;
  #pragma unroll
  for (int h = 0; h < H1; ++h)
    s = fmaf(__shfl(g1, h), sW1T[h*DF + dl], s);

  if (lane < DF) dG[atom*DF + lane] = s;
  if (lane == 0) Ei_ws[atom] = eip + b3[0];
}

// ---------------- Kernel 2: Force[b,i,c] = sum_{j,f} dG[b,j,f]*dfeat[b,i,j,f,c]
// grid = 256 blocks x 1024 threads (16 waves), 1 block/CU, one clean round.
// Block owns 8 contiguous rows of one batch (1.03 MB). Loop order is
// row-OUTER / m-inner (R7's sequential-stream order, which measured best),
// but the shuffle-reduce chains are DEFERRED: row r accumulates into
// acc[r][slot] (24 statically-indexed VGPRs; both loops fully unrolled) and
// all 8 reduces run once at the end. Between rows there is no dependent
// chain and no vmcnt drain -> the VMEM queue stays full across row
// boundaries (R8 tested deferred reduces but with m-outer load order, which
// scattered each wave's loads across 8 rows and regressed; this isolates
// the deferral with unchanged load order).
__global__ __launch_bounds__(1024, 4) void k2_force(
    const float* __restrict__ dfeat,
    const float* __restrict__ dG,
    const float* __restrict__ Ei_ws,
    float* __restrict__ out) {
  __shared__ float dgLf[NATOM*DF];      // 10752 floats = 43008 B
  __shared__ float red[8][16][3];       // [row][wave][c]
  __shared__ float ered[4];

  const int tid = threadIdx.x;
  const int blk = blockIdx.x;
  const int b = blk >> 5;               // batch (constant per block)

  // stage dG[b] -> LDS (vectorized): 2688 float4 = 1024*2 + 640
  const f32x4* __restrict__ dgg = (const f32x4*)(dG + b*(NATOM*DF));
  f32x4* dgv = (f32x4*)dgLf;
  dgv[tid]        = dgg[tid];
  dgv[tid + 1024] = dgg[tid + 1024];
  if (tid < 640) dgv[tid + 2048] = dgg[tid + 2048];

  // fold Etot[b]: first block of each batch reduces Ei (waves 0-3)
  if ((blk & 31) == 0 && tid < 256) {
    float e = Ei_ws[b*NATOM + tid];
    #pragma unroll
    for (int off = 32; off; off >>= 1) e += __shfl_down(e, off);
    if ((tid & 63) == 0) ered[tid >> 6] = e;
  }
  __syncthreads();

  const int wv  = tid >> 6;
  const int f0i = (4*tid)/3;            // feature index of element 4*tid
  const int rqi = tid - (tid/3)*3;      // tid % 3  (= 4*tid mod 3)

  // base float4 pointer; row r, step m at base[r*8064 + m*1024]
  const f32x4* __restrict__ base =
      (const f32x4*)(dfeat + (size_t)blk * (8*NATOM*DF*3)) + tid;

  float acc[8][3];
  #pragma unroll
  for (int r = 0; r < 8; ++r) { acc[r][0] = 0.f; acc[r][1] = 0.f; acc[r][2] = 0.f; }

  // float4 q = tid + 1024*m of a row: elems k=4q+j, c=(rqi+m+j)%3 -> slot
  // (m+j)%3 (compile-time). j=0 -> dG[f0]; j=3 -> dG[f0+1];
  // j=1 -> f0+(rq==2); j=2 -> f0+(rq>=1). 8064 = 1024*7 + 896.
  #pragma unroll
  for (int r = 0; r < 8; ++r) {
    int f0 = f0i, rq = rqi;             // rq = (rqi + m) % 3 at step m
    #pragma unroll
    for (int m = 0; m < 8; ++m) {
      if (m < 7 || tid < 896) {
        f32x4 v = base[r*8064 + m*1024];
        float gLo = dgLf[f0];
        float gHi = dgLf[f0+1];
        float gm1 = (rq < 2) ? gLo : gHi;
        float gm2 = (rq < 1) ? gLo : gHi;
        acc[r][(m+0)%3] = fmaf(v.x, gLo, acc[r][(m+0)%3]);
        acc[r][(m+1)%3] = fmaf(v.y, gm1, acc[r][(m+1)%3]);
        acc[r][(m+2)%3] = fmaf(v.z, gm2, acc[r][(m+2)%3]);
        acc[r][(m+0)%3] = fmaf(v.w, gHi, acc[r][(m+0)%3]);
      }
      f0 += 1365 + (rq == 2 ? 1 : 0);   // 4q += 4096 = 3*1365 + 1
      rq = (rq == 2) ? 0 : rq + 1;
    }
  }

  // slot s holds true c = (rqi + s) % 3 -> rotate back, then reduce all rows
  #pragma unroll
  for (int r = 0; r < 8; ++r) {
    float tx = (rqi == 0) ? acc[r][0] : (rqi == 1) ? acc[r][2] : acc[r][1];
    float ty = (rqi == 0) ? acc[r][1] : (rqi == 1) ? acc[r][0] : acc[r][2];
    float tz = (rqi == 0) ? acc[r][2] : (rqi == 1) ? acc[r][1] : acc[r][0];
    #pragma unroll
    for (int off = 32; off; off >>= 1) {
      tx += __shfl_down(tx, off);
      ty += __shfl_down(ty, off);
      tz += __shfl_down(tz, off);
    }
    if ((tid & 63) == 0) { red[r][wv][0] = tx; red[r][wv][1] = ty; red[r][wv][2] = tz; }
  }

  __syncthreads();
  if (tid < 24) {             // 8 rows x 3 components
    const int rr = tid / 3;
    const int c  = tid - rr*3;
    float s = 0.f;
    #pragma unroll
    for (int w = 0; w < 16; ++w) s += red[rr][w][c];
    out[BATCH + (size_t)(blk*8 + rr)*3 + c] = s;
  }
  if ((blk & 31) == 0 && tid == 24)
    out[b] = ered[0] + ered[1] + ered[2] + ered[3];
}

extern "C" void kernel_launch(void* const* d_in, const int* in_sizes, int n_in,
                              void* d_out, int out_size, void* d_ws, size_t ws_size,
                              hipStream_t stream) {
  const float* image = (const float*)d_in[0];
  const float* dfeat = (const float*)d_in[1];
  const float* W1    = (const float*)d_in[2];
  const float* b1    = (const float*)d_in[3];
  const float* W2    = (const float*)d_in[4];
  const float* b2    = (const float*)d_in[5];
  const float* W3    = (const float*)d_in[6];
  const float* b3    = (const float*)d_in[7];
  float* out = (float*)d_out;

  float* dG = (float*)d_ws;                       // B*N*DF floats
  float* Ei = dG + BATCH*NATOM*DF;                // B*N floats

  k1_mlp<<<BATCH*NATOM/4, 256, 0, stream>>>(image, W1, b1, W2, b2, W3, b3, dG, Ei);
  k2_force<<<BATCH*NATOM/8, 1024, 0, stream>>>(dfeat, dG, Ei, out);
}

// Round 10
// 55.195 us; speedup vs baseline: 1.1351x; 1.1351x over previous
//
#include <hip/hip_runtime.h>

#define BATCH 8
#define NATOM 256
#define DF    42
#define H1    64
#define H2    32

typedef float f32x4 __attribute__((ext_vector_type(4)));

__device__ __forceinline__ float softplus_f(float z) {
  return fmaxf(z, 0.f) + log1pf(expf(-fabsf(z)));
}

// ---------------- Kernel 1: per-atom mirrored MLP (fwd + analytic bwd) ----
// grid = B*N/4 blocks, 256 threads (4 waves). One wave per atom.
__global__ __launch_bounds__(256) void k1_mlp(
    const float* __restrict__ image,
    const float* __restrict__ W1, const float* __restrict__ b1,
    const float* __restrict__ W2, const float* __restrict__ b2,
    const float* __restrict__ W3, const float* __restrict__ b3,
    float* __restrict__ dG, float* __restrict__ Ei_ws) {
  __shared__ float sW1 [DF*H1];   // [d][h]
  __shared__ float sW1T[H1*DF];   // [h][d]
  __shared__ float sW2 [H1*H2];   // [h1][h2]
  __shared__ float sW2T[H2*H1];   // [h2][h1]
  __shared__ float sW3[H2], sb1[H1], sb2[H2];

  const int tid = threadIdx.x;
  for (int idx = tid; idx < DF*H1; idx += 256) {
    float w = W1[idx];
    sW1[idx] = w;
    sW1T[(idx & (H1-1))*DF + (idx >> 6)] = w;   // idx = d*64+h
  }
  for (int idx = tid; idx < H1*H2; idx += 256) {
    float w = W2[idx];
    sW2[idx] = w;
    sW2T[(idx & (H2-1))*H1 + (idx >> 5)] = w;   // idx = h1*32+h2
  }
  if (tid < H2)                    { sW3[tid] = W3[tid]; sb2[tid] = b2[tid]; }
  else if (tid >= 64 && tid < 128) { sb1[tid-64] = b1[tid-64]; }
  __syncthreads();

  const int lane = tid & 63;
  const int atom = blockIdx.x * 4 + (tid >> 6);      // 0..B*N-1

  float xv = (lane < DF) ? image[atom*DF + lane] : 0.f;

  // layer 1: z1[h] = b1[h] + sum_d x[d]*W1[d][h]   (lane = h)
  float z1 = sb1[lane];
  #pragma unroll
  for (int d = 0; d < DF; ++d)
    z1 = fmaf(__shfl(xv, d), sW1[d*H1 + lane], z1);
  float a1 = softplus_f(z1);

  // layer 2: lanes duplicated mod 32 (lane&31 = h2)
  const int h2l = lane & (H2-1);
  float z2 = sb2[h2l];
  #pragma unroll
  for (int h = 0; h < H1; ++h)
    z2 = fmaf(__shfl(a1, h), sW2[h*H2 + h2l], z2);
  float a2 = softplus_f(z2);

  // Ei = b3 + sum_h2 a2*W3 ;  g2 = sigmoid(z2)*W3 ; sigmoid(z)=1-exp(-softplus(z))
  float w3  = sW3[h2l];
  float eip = a2 * w3;
  #pragma unroll
  for (int off = 16; off; off >>= 1) eip += __shfl_xor(eip, off);
  float g2 = (1.f - expf(-a2)) * w3;

  // g1[h] = sigmoid(z1[h]) * sum_h2 g2[h2]*W2[h][h2]
  float t1 = 0.f;
  #pragma unroll
  for (int h2 = 0; h2 < H2; ++h2)
    t1 = fmaf(__shfl(g2, h2), sW2T[h2*H1 + lane], t1);
  float g1 = (1.f - expf(-a1)) * t1;

  // dG[d] = sum_h g1[h]*W1[d][h]    (lane = d, lanes 0..41)
  const int dl = (lane < DF) ? lane : 0;
  float s = 0.f;
  #pragma unroll
  for (int h = 0; h < H1; ++h)
    s = fmaf(__shfl(g1, h), sW1T[h*DF + dl], s);

  if (lane < DF) dG[atom*DF + lane] = s;
  if (lane == 0) Ei_ws[atom] = eip + b3[0];
}

// ---------------- Kernel 2: Force[b,i,c] = sum_{j,f} dG[b,j,f]*dfeat[b,i,j,f,c]
// grid = 256 blocks x 1024 threads (16 waves), 1 block/CU, one clean round.
// Block owns 8 contiguous rows of one batch (1.03 MB); row-outer / m-inner
// with per-row shuffle reduce (R7 structure, measured best at 56.4 us).
// ISOLATED CHANGE vs R7: dfeat loads are NON-TEMPORAL (no L2 allocate).
// Theory: the one-pass 264 MB read stream otherwise allocates+evicts every
// line in L2; if TCC streaming-allocation overhead is the ~20% wall, nt
// removes it. dG stays in LDS (lgkmcnt path), dfeat owns the vmcnt queue.
__global__ __launch_bounds__(1024, 4) void k2_force(
    const float* __restrict__ dfeat,
    const float* __restrict__ dG,
    const float* __restrict__ Ei_ws,
    float* __restrict__ out) {
  __shared__ float dgLf[NATOM*DF];      // 10752 floats = 43008 B
  __shared__ float red[8][16][3];       // [row][wave][c]
  __shared__ float ered[4];

  const int tid = threadIdx.x;
  const int blk = blockIdx.x;
  const int b = blk >> 5;               // batch (constant per block)

  // stage dG[b] -> LDS (vectorized): 2688 float4 = 1024*2 + 640
  const f32x4* __restrict__ dgg = (const f32x4*)(dG + b*(NATOM*DF));
  f32x4* dgv = (f32x4*)dgLf;
  dgv[tid]        = dgg[tid];
  dgv[tid + 1024] = dgg[tid + 1024];
  if (tid < 640) dgv[tid + 2048] = dgg[tid + 2048];

  // fold Etot[b]: first block of each batch reduces Ei (waves 0-3)
  if ((blk & 31) == 0 && tid < 256) {
    float e = Ei_ws[b*NATOM + tid];
    #pragma unroll
    for (int off = 32; off; off >>= 1) e += __shfl_down(e, off);
    if ((tid & 63) == 0) ered[tid >> 6] = e;
  }
  __syncthreads();

  const int wv  = tid >> 6;
  const int f0i = (4*tid)/3;            // feature index of element 4*tid
  const int rqi = tid - (tid/3)*3;      // tid % 3  (= 4*tid mod 3)

  #pragma unroll 1
  for (int r = 0; r < 8; ++r) {
    const f32x4* __restrict__ p4 =
        (const f32x4*)(dfeat + (size_t)(blk*8 + r) * (NATOM*DF*3)) + tid;

    float a0 = 0.f, a1 = 0.f, a2 = 0.f;
    int f0 = f0i, rq = rqi;             // rq = (rqi + m) % 3 at step m

    // float4 q = tid + 1024*m: elems k=4q+j, c=(rqi+m+j)%3 -> slot (m+j)%3.
    // j=0: f=f0; j=3: f=f0+1; j=1: f=f0+(rq==2); j=2: f=f0+(rq>=1).
    auto iter = [&](float& pa, float& pb, float& pc, int m) {
      f32x4 v = __builtin_nontemporal_load(p4 + m*1024);
      float gLo = dgLf[f0];
      float gHi = dgLf[f0+1];
      float gm1 = (rq < 2) ? gLo : gHi;
      float gm2 = (rq < 1) ? gLo : gHi;
      pa = fmaf(v.x, gLo, pa);          // j=0 -> slot (m)%3
      pb = fmaf(v.y, gm1, pb);          // j=1 -> slot (m+1)%3
      pc = fmaf(v.z, gm2, pc);          // j=2 -> slot (m+2)%3
      pa = fmaf(v.w, gHi, pa);          // j=3 -> slot (m)%3
      f0 += 1365 + (rq == 2 ? 1 : 0);   // 4q += 4096 = 3*1365 + 1
      rq = (rq == 2) ? 0 : rq + 1;
    };

    // 8064 float4/row = 1024*7 + 896: m=0..6 uniform, m=7 for tid<896
    iter(a0, a1, a2, 0);
    iter(a1, a2, a0, 1);
    iter(a2, a0, a1, 2);
    iter(a0, a1, a2, 3);
    iter(a1, a2, a0, 4);
    iter(a2, a0, a1, 5);
    iter(a0, a1, a2, 6);
    if (tid < 896) iter(a1, a2, a0, 7);

    // slot s holds true c = (rqi + s) % 3 -> rotate back
    float tx = (rqi == 0) ? a0 : (rqi == 1) ? a2 : a1;
    float ty = (rqi == 0) ? a1 : (rqi == 1) ? a0 : a2;
    float tz = (rqi == 0) ? a2 : (rqi == 1) ? a1 : a0;

    #pragma unroll
    for (int off = 32; off; off >>= 1) {
      tx += __shfl_down(tx, off);
      ty += __shfl_down(ty, off);
      tz += __shfl_down(tz, off);
    }
    if ((tid & 63) == 0) { red[r][wv][0] = tx; red[r][wv][1] = ty; red[r][wv][2] = tz; }
  }

  __syncthreads();
  if (tid < 24) {             // 8 rows x 3 components
    const int rr = tid / 3;
    const int c  = tid - rr*3;
    float s = 0.f;
    #pragma unroll
    for (int w = 0; w < 16; ++w) s += red[rr][w][c];
    out[BATCH + (size_t)(blk*8 + rr)*3 + c] = s;
  }
  if ((blk & 31) == 0 && tid == 24)
    out[b] = ered[0] + ered[1] + ered[2] + ered[3];
}

extern "C" void kernel_launch(void* const* d_in, const int* in_sizes, int n_in,
                              void* d_out, int out_size, void* d_ws, size_t ws_size,
                              hipStream_t stream) {
  const float* image = (const float*)d_in[0];
  const float* dfeat = (const float*)d_in[1];
  const float* W1    = (const float*)d_in[2];
  const float* b1    = (const float*)d_in[3];
  const float* W2    = (const float*)d_in[4];
  const float* b2    = (const float*)d_in[5];
  const float* W3    = (const float*)d_in[6];
  const float* b3    = (const float*)d_in[7];
  float* out = (float*)d_out;

  float* dG = (float*)d_ws;                       // B*N*DF floats
  float* Ei = dG + BATCH*NATOM*DF;                // B*N floats

  k1_mlp<<<BATCH*NATOM/4, 256, 0, stream>>>(image, W1, b1, W2, b2, W3, b3, dG, Ei);
  k2_force<<<BATCH*NATOM/8, 1024, 0, stream>>>(dfeat, dG, Ei, out);
}